// Round 1
// baseline (3503.585 us; speedup 1.0000x reference)
//
#include <hip/hip_runtime.h>

typedef float v4 __attribute__((ext_vector_type(4)));
typedef float v2 __attribute__((ext_vector_type(2)));

#define BLOCK 512
#define RROWS 64

constexpr int XC   = 224;  // x columns
constexpr int HREV = 32;   // buf width
constexpr int HFWD = 64;   // steps / output width
constexpr int U    = 128;  // hidden units
// LDS layout (floats)
constexpr int W1_FL  = 97 * U;        // 12416
constexpr int W2_FL  = U * U;         // 16384
constexpr int H1_FL  = RROWS * U;     // 8192
constexpr int BUF_FL = RROWS * HREV;  // 2048
constexpr int LDS_FL = W1_FL + W2_FL + H1_FL + BUF_FL; // 39040 fl = 156160 B

extern "C" __global__ __launch_bounds__(BLOCK, 2)
void rmlp_kernel(const float* __restrict__ x, const float* __restrict__ W1,
                 const float* __restrict__ b1, const float* __restrict__ W2,
                 const float* __restrict__ b2, const float* __restrict__ W3,
                 const float* __restrict__ b3, float* __restrict__ out)
{
    extern __shared__ float lds[];
    float* W1s  = lds;               // [97][128]
    float* W2s  = W1s + W1_FL;       // [128][128]
    float* h1s  = W2s + W2_FL;       // [64][128]
    float* bufs = h1s + H1_FL;       // [64][32] recurrent buffer

    const int t  = threadIdx.x;
    const int nt = t & 31;           // neuron tile 0..31  (n = 4*nt .. +3)
    const int rt = t >> 5;           // row tile   0..15  (r = 4*rt .. +3)
    const int n0 = nt << 2;
    const int r0 = rt << 2;
    const long row0 = (long)blockIdx.x * RROWS;

    // ---- stage weights into LDS (vectorized) ----
    {
        const v4* g1 = (const v4*)W1; v4* s1 = (v4*)W1s;
        for (int idx = t; idx < W1_FL / 4; idx += BLOCK) s1[idx] = g1[idx];
        const v4* g2 = (const v4*)W2; v4* s2 = (v4*)W2s;
        for (int idx = t; idx < W2_FL / 4; idx += BLOCK) s2[idx] = g2[idx];
    }
    // ---- buf init: e = x[:, :32] ----
    {
        int br = t >> 3, bc = t & 7;
        v4 e = *(const v4*)(x + (row0 + br) * XC + bc * 4);
        ((v4*)bufs)[br * 8 + bc] = e;
    }
    // per-thread hoisted vectors (fixed by neuron tile)
    float b1v[4], b2v[4], w3v[4], w196[4];
    #pragma unroll
    for (int j = 0; j < 4; ++j) {
        b1v[j]  = b1[n0 + j];
        b2v[j]  = b2[n0 + j];
        w3v[j]  = W3[n0 + j];
        w196[j] = W1[96 * U + n0 + j];   // the "i * ones" column of W1
    }
    const float b3s = b3[0];

    const float* xr[4];
    #pragma unroll
    for (int rr = 0; rr < 4; ++rr)
        xr[rr] = x + (row0 + r0 + rr) * XC + HREV;   // v window base

    float* outb = out + row0 * HFWD;

    const int srow = t >> 3;          // shift duty: row, cols sc..sc+3
    const int sc   = (t & 7) * 4;

    __syncthreads();

    const v4* W1s4 = (const v4*)W1s;
    const v4* W2s4 = (const v4*)W2s;
    const v4* h1s4 = (const v4*)h1s;
    const v4* buf4 = (const v4*)bufs;

    for (int i = 0; i < HFWD; ++i) {
        const float fi = (float)i;
        // ---------- layer 1 : data(97) @ W1 -> h1(128), relu ----------
        float a1[4][4];
        #pragma unroll
        for (int rr = 0; rr < 4; ++rr)
            #pragma unroll
            for (int j = 0; j < 4; ++j)
                a1[rr][j] = fmaf(fi, w196[j], b1v[j]);

        // k = 0..31 : buf part (LDS)
        #pragma unroll 4
        for (int kc = 0; kc < 8; ++kc) {
            v4 w[4];
            #pragma unroll
            for (int kk = 0; kk < 4; ++kk) w[kk] = W1s4[(kc * 4 + kk) * 32 + nt];
            #pragma unroll
            for (int rr = 0; rr < 4; ++rr) {
                v4 d = buf4[(r0 + rr) * 8 + kc];
                #pragma unroll
                for (int kk = 0; kk < 4; ++kk)
                    #pragma unroll
                    for (int j = 0; j < 4; ++j)
                        a1[rr][j] = fmaf(d[kk], w[kk][j], a1[rr][j]);
            }
        }
        // k = 32..95 : v part, contiguous x[r, 32+2i .. 95+2i] (global, L1-hot)
        #pragma unroll 4
        for (int qc = 0; qc < 16; ++qc) {
            v4 w[4];
            #pragma unroll
            for (int kk = 0; kk < 4; ++kk) w[kk] = W1s4[(HREV + qc * 4 + kk) * 32 + nt];
            #pragma unroll
            for (int rr = 0; rr < 4; ++rr) {
                const float* p = xr[rr] + 2 * i + qc * 4;   // 8B-aligned always
                v2 lo = *(const v2*)p;
                v2 hi = *(const v2*)(p + 2);
                float d0 = lo[0], d1 = lo[1], d2 = hi[0], d3 = hi[1];
                #pragma unroll
                for (int j = 0; j < 4; ++j) {
                    a1[rr][j] = fmaf(d0, w[0][j], a1[rr][j]);
                    a1[rr][j] = fmaf(d1, w[1][j], a1[rr][j]);
                    a1[rr][j] = fmaf(d2, w[2][j], a1[rr][j]);
                    a1[rr][j] = fmaf(d3, w[3][j], a1[rr][j]);
                }
            }
        }
        // write h1 = relu(a1)
        #pragma unroll
        for (int rr = 0; rr < 4; ++rr) {
            v4 h;
            #pragma unroll
            for (int j = 0; j < 4; ++j) h[j] = fmaxf(a1[rr][j], 0.0f);
            ((v4*)h1s)[(r0 + rr) * 32 + nt] = h;
        }
        // shift-read old buf (phase 1: no writers until after barrier)
        float sv0 = bufs[srow * HREV + sc + 1];
        float sv1 = bufs[srow * HREV + sc + 2];
        float sv2 = bufs[srow * HREV + sc + 3];
        float sv3 = (sc + 4 < HREV) ? bufs[srow * HREV + sc + 4] : 0.0f;

        __syncthreads();   // h1 ready; all buf reads done

        // ---------- layer 2 : h1 @ W2 -> h2(128), relu ----------
        float a2[4][4];
        #pragma unroll
        for (int rr = 0; rr < 4; ++rr)
            #pragma unroll
            for (int j = 0; j < 4; ++j)
                a2[rr][j] = b2v[j];
        #pragma unroll 4
        for (int jc = 0; jc < 32; ++jc) {
            v4 w[4];
            #pragma unroll
            for (int kk = 0; kk < 4; ++kk) w[kk] = W2s4[(jc * 4 + kk) * 32 + nt];
            #pragma unroll
            for (int rr = 0; rr < 4; ++rr) {
                v4 h = h1s4[(r0 + rr) * 32 + jc];
                #pragma unroll
                for (int kk = 0; kk < 4; ++kk)
                    #pragma unroll
                    for (int j = 0; j < 4; ++j)
                        a2[rr][j] = fmaf(h[kk], w[kk][j], a2[rr][j]);
            }
        }
        // ---------- layer 3 : relu(h2) @ W3 + b3, cross-lane reduce ----------
        float wv[4];
        #pragma unroll
        for (int rr = 0; rr < 4; ++rr) {
            float p = 0.0f;
            #pragma unroll
            for (int j = 0; j < 4; ++j)
                p = fmaf(fmaxf(a2[rr][j], 0.0f), w3v[j], p);
            #pragma unroll
            for (int off = 16; off >= 1; off >>= 1)
                p += __shfl_xor(p, off, 64);   // masks <=16 stay within 32-lane halves
            wv[rr] = p + b3s;
        }
        // ---------- writes: output, buf shift + append w ----------
        if (nt == 0) {
            #pragma unroll
            for (int rr = 0; rr < 4; ++rr) {
                bufs[(r0 + rr) * HREV + 31] = wv[rr];
                outb[(long)(r0 + rr) * HFWD + i] = wv[rr];
            }
        }
        bufs[srow * HREV + sc + 0] = sv0;
        bufs[srow * HREV + sc + 1] = sv1;
        bufs[srow * HREV + sc + 2] = sv2;
        if (sc + 3 < HREV - 1) bufs[srow * HREV + sc + 3] = sv3;
        __syncthreads();   // buf writes done before next step's reads
    }
}

extern "C" void kernel_launch(void* const* d_in, const int* in_sizes, int n_in,
                              void* d_out, int out_size, void* d_ws, size_t ws_size,
                              hipStream_t stream) {
    const float* x  = (const float*)d_in[0];
    const float* W1 = (const float*)d_in[1];
    const float* b1 = (const float*)d_in[2];
    const float* W2 = (const float*)d_in[3];
    const float* b2 = (const float*)d_in[4];
    const float* W3 = (const float*)d_in[5];
    const float* b3 = (const float*)d_in[6];
    float* out = (float*)d_out;

    const int B = in_sizes[0] / XC;          // 65536
    const int grid = B / RROWS;              // 1024 blocks

    // 156160 B dynamic LDS > default 64 KB cap -> opt in (idempotent, graph-safe)
    hipFuncSetAttribute((const void*)rmlp_kernel,
                        hipFuncAttributeMaxDynamicSharedMemorySize, LDS_FL * 4);

    rmlp_kernel<<<grid, BLOCK, LDS_FL * 4, stream>>>(x, W1, b1, W2, b2, W3, b3, out);
}